// Round 11
// baseline (126.534 us; speedup 1.0000x reference)
//
#include <hip/hip_runtime.h>
#include <hip/hip_bf16.h>
#include <stdint.h>

#define GAMMA 1e-4f

typedef int i32x4 __attribute__((ext_vector_type(4)));
typedef int i32x8 __attribute__((ext_vector_type(8)));
typedef float f32x4 __attribute__((ext_vector_type(4)));

__device__ __forceinline__ float bf2f(unsigned short u) {
  unsigned int x = ((unsigned int)u) << 16;
  float f; __builtin_memcpy(&f, &x, 4);
  return f;
}

// bit-exact float -> OCP e4m3fn (RNE, satfinite).
__device__ __forceinline__ unsigned char f2e4m3(float x) {
  float a = fabsf(x);
  unsigned char s = x < 0.f ? 0x80 : 0;
  a = fminf(a, 448.f);
  if (a < 0.015625f) {                    // subnormal region, ulp 2^-9
    int q = (int)rintf(a * 512.f);
    return s | (unsigned char)q;
  }
  unsigned int u; __builtin_memcpy(&u, &a, 4);
  u += 0x7FFFFu + ((u >> 20) & 1);        // RNE to 3 mantissa bits
  u &= 0xFFF00000u;
  int e2 = (int)(u >> 23) - 127;
  unsigned int mant = (u >> 20) & 7;
  return s | (unsigned char)(((e2 + 7) << 3) | mant);
}

__device__ __forceinline__ unsigned int pack4(float a, float b, float c, float d) {
  return (unsigned)f2e4m3(a) | ((unsigned)f2e4m3(b) << 8) |
         ((unsigned)f2e4m3(c) << 16) | ((unsigned)f2e4m3(d) << 24);
}

// ---------------- Kernel 1: merged prep (fp8 outputs, fp32 norms) ----------------
__global__ __launch_bounds__(256) void prep_k(
    const float* __restrict__ x, const float* __restrict__ cw,
    const float* __restrict__ cb, unsigned char* __restrict__ fA8,
    float* __restrict__ f2, const float* __restrict__ pr,
    unsigned char* __restrict__ pB8, float* __restrict__ p2) {
  const int tid = threadIdx.x;
  __shared__ float red[4];
  if (blockIdx.x < 4096) {
    const int j = blockIdx.x;
    const float4* src = (const float4*)(pr + (size_t)j * 4096);
    float ssq = 0.f;
    unsigned int w4[4];
#pragma unroll
    for (int k = 0; k < 4; k++) {
      float4 v = src[tid * 4 + k];
      ssq += v.x * v.x + v.y * v.y + v.z * v.z + v.w * v.w;
      w4[k] = pack4(v.x, v.y, v.z, v.w);
    }
    *(uint4*)(pB8 + (size_t)j * 4096 + tid * 16) = make_uint4(w4[0], w4[1], w4[2], w4[3]);
    for (int off = 32; off > 0; off >>= 1) ssq += __shfl_down(ssq, off);
    if ((tid & 63) == 0) red[tid >> 6] = ssq;
    __syncthreads();
    if (tid == 0) p2[j] = red[0] + red[1] + red[2] + red[3];
  } else {
    const int b = blockIdx.x - 4096;
    __shared__ float swb[20];
    if (tid < 16) swb[tid] = cw[tid];
    else if (tid < 20) swb[tid] = cb[tid - 16];
    __syncthreads();
    float w[16], bias[4];
#pragma unroll
    for (int i = 0; i < 16; i++) w[i] = swb[i];
#pragma unroll
    for (int c = 0; c < 4; c++) bias[c] = swb[16 + c];
    const float* xb = x + (size_t)b * 4096;
    unsigned char* fb8 = fA8 + (size_t)b * 4096;
    const int p0 = tid * 4;
    const int h = p0 >> 5, w0 = p0 & 31;
    const float* r0 = xb + (2 * h) * 64 + 2 * w0;
    const float* r1 = r0 + 64;
    float4 a0 = *(const float4*)r0, a1 = *(const float4*)(r0 + 4);
    float4 c0 = *(const float4*)r1, c1 = *(const float4*)(r1 + 4);
    float ssq = 0.f;
#pragma unroll
    for (int c = 0; c < 4; c++) {
      float w00 = w[c * 4], w01 = w[c * 4 + 1], w10 = w[c * 4 + 2], w11 = w[c * 4 + 3];
      float v0 = bias[c] + a0.x * w00 + a0.y * w01 + c0.x * w10 + c0.y * w11;
      float v1 = bias[c] + a0.z * w00 + a0.w * w01 + c0.z * w10 + c0.w * w11;
      float v2 = bias[c] + a1.x * w00 + a1.y * w01 + c1.x * w10 + c1.y * w11;
      float v3 = bias[c] + a1.z * w00 + a1.w * w01 + c1.z * w10 + c1.w * w11;
      ssq += v0 * v0 + v1 * v1 + v2 * v2 + v3 * v3;
      *(unsigned int*)(fb8 + c * 1024 + p0) = pack4(v0, v1, v2, v3);
    }
    for (int off = 32; off > 0; off >>= 1) ssq += __shfl_down(ssq, off);
    if ((tid & 63) == 0) red[tid >> 6] = ssq;
    __syncthreads();
    if (tid == 0) f2[b] = red[0] + red[1] + red[2] + red[3];
  }
}

// ---------------- Kernel 2: fp8 GEMM (16x16x128 mfma_scale) + RBF epilogue ------------
// BM=128, BN=256, BK=128; 8 waves (2M x 4N).
// A OPERAND DIRECT FROM GLOBAL TO REGISTERS (L1/L2-resident, lane-private rows)
//   - double-buffered in named Xa/Ya sets, re-issued at body end after last use.
// B ONLY in LDS: ring-3 x 32 KiB = 96 KiB; SWZB fragment geometry (0 conflicts).
// One barrier per tile; counted vmcnt(12) = {4 B-GLDS(t+2) + 8 A-loads(t+2)} in
// flight -> B(t+1) staged & A(t+1) landed proven; lgkm(4)/(0) two-phase MFMA.
#define SWZB(o) ((o) ^ ((((o) >> 13) & 1) << 4))
#define TILE_BYTES 32768

#define GLDS(gsrc, ldst)                                                    \
  __builtin_amdgcn_global_load_lds(                                         \
      (__attribute__((address_space(1))) void*)(void*)(gsrc),               \
      (__attribute__((address_space(3))) void*)(ldst), 16, 0, 0)

#define MFMA8(a, b, c)                                                      \
  __builtin_amdgcn_mfma_scale_f32_16x16x128_f8f6f4(                         \
      (a), (b), (c), 0, 0, 0, 0x7f7f7f7fu, 0, 0x7f7f7f7fu)

__device__ __forceinline__ i32x8 read32(const char* p0, const char* p1) {
  i32x4 lo = *(const i32x4*)p0;
  i32x4 hi = *(const i32x4*)p1;
  return __builtin_shufflevector(lo, hi, 0, 1, 2, 3, 4, 5, 6, 7);
}
__device__ __forceinline__ i32x8 read_a(const unsigned char* p) {
  i32x4 lo = *(const i32x4*)p;
  i32x4 hi = *(const i32x4*)(p + 16);
  return __builtin_shufflevector(lo, hi, 0, 1, 2, 3, 4, 5, 6, 7);
}

#define SB __builtin_amdgcn_sched_barrier(0)

// body t: MFMA on A-set AX (=A(t), landed), B frags from CUR; stage B(t+2)->STG;
// reissue AX <- A(t+2) after last use; vmcnt(12); barrier publishes B(t+1).
#define TBODY(CUR, STG, AX0, AX1, AX2, AX3, KB)                             \
  {                                                                         \
    i32x8 bv0, bv1, bv2, bv3;                                               \
    SB;                                                                     \
    bv0 = read32((CUR) + brlo[0], (CUR) + brhi[0]);                         \
    bv1 = read32((CUR) + brlo[1], (CUR) + brhi[1]);                         \
    SB;                                                                     \
    GLDS(bgp[0] + (KB), (STG) + boff[0]);                                   \
    GLDS(bgp[1] + (KB), (STG) + boff[1]);                                   \
    GLDS(bgp[2] + (KB), (STG) + boff[2]);                                   \
    GLDS(bgp[3] + (KB), (STG) + boff[3]);                                   \
    SB;                                                                     \
    bv2 = read32((CUR) + brlo[2], (CUR) + brhi[2]);                         \
    bv3 = read32((CUR) + brlo[3], (CUR) + brhi[3]);                         \
    SB;                                                                     \
    asm volatile("s_waitcnt lgkmcnt(4)" ::: "memory");                      \
    SB;                                                                     \
    __builtin_amdgcn_s_setprio(1);                                          \
    acc[0][0] = MFMA8(AX0, bv0, acc[0][0]);                                 \
    acc[0][1] = MFMA8(AX0, bv1, acc[0][1]);                                 \
    acc[1][0] = MFMA8(AX1, bv0, acc[1][0]);                                 \
    acc[1][1] = MFMA8(AX1, bv1, acc[1][1]);                                 \
    acc[2][0] = MFMA8(AX2, bv0, acc[2][0]);                                 \
    acc[2][1] = MFMA8(AX2, bv1, acc[2][1]);                                 \
    acc[3][0] = MFMA8(AX3, bv0, acc[3][0]);                                 \
    acc[3][1] = MFMA8(AX3, bv1, acc[3][1]);                                 \
    __builtin_amdgcn_s_setprio(0);                                          \
    SB;                                                                     \
    asm volatile("s_waitcnt lgkmcnt(0)" ::: "memory");                      \
    SB;                                                                     \
    __builtin_amdgcn_s_setprio(1);                                          \
    acc[0][2] = MFMA8(AX0, bv2, acc[0][2]);                                 \
    acc[0][3] = MFMA8(AX0, bv3, acc[0][3]);                                 \
    acc[1][2] = MFMA8(AX1, bv2, acc[1][2]);                                 \
    acc[1][3] = MFMA8(AX1, bv3, acc[1][3]);                                 \
    acc[2][2] = MFMA8(AX2, bv2, acc[2][2]);                                 \
    acc[2][3] = MFMA8(AX2, bv3, acc[2][3]);                                 \
    acc[3][2] = MFMA8(AX3, bv2, acc[3][2]);                                 \
    acc[3][3] = MFMA8(AX3, bv3, acc[3][3]);                                 \
    __builtin_amdgcn_s_setprio(0);                                          \
    SB;                                                                     \
    AX0 = read_a(ag[0] + (KB));  /* reissue A(t+2) after last use of AX */  \
    AX1 = read_a(ag[1] + (KB));                                             \
    AX2 = read_a(ag[2] + (KB));                                             \
    AX3 = read_a(ag[3] + (KB));                                             \
    SB;                                                                     \
    asm volatile("s_waitcnt vmcnt(12)" ::: "memory");                       \
    SB;                                                                     \
    __builtin_amdgcn_s_barrier();                                           \
  }

__global__ __launch_bounds__(512, 1) void gemm_kv_k(
    const unsigned char* __restrict__ A, const unsigned char* __restrict__ B,
    const float* __restrict__ f2, const float* __restrict__ p2,
    __hip_bfloat16* __restrict__ kv) {
  __shared__ __align__(16) char lds[3 * TILE_BYTES];  // 96 KiB, B only
  const int tid = threadIdx.x;
  const int wave = tid >> 6, lane = tid & 63;
  const int q = lane >> 4, l16 = lane & 15;
  const int wr = wave >> 2, wc = wave & 3;

  // XCD-aware tile swizzle: 256 WGs = 8 XCDs x 32
  const int wg = blockIdx.x;
  const int xcd = wg & 7, loc = wg >> 3;
  const int bm = (xcd & 1) * 8 + (loc & 7);
  const int bn = (xcd >> 1) * 4 + (loc >> 3);

  // B staging: linear LDS dest, inverse-swizzled global src (rule #21)
  const unsigned char* bgp[4];
  int boff[4];
#pragma unroll
  for (int i = 0; i < 4; i++) {
    int phys = (tid + i * 512) * 16;   // [0, 32768)
    boff[i] = phys;
    int lg = SWZB(phys);
    int kq = lg >> 13, rw = (lg & 8191) >> 5, kl = lg & 31;
    bgp[i] = B + (size_t)(bn * 256 + rw) * 4096 + kq * 32 + kl;
  }

  // B fragment read addresses (R5-verified geometry, 0 conflicts; base 0 now)
  int brlo[4], brhi[4];
#pragma unroll
  for (int n = 0; n < 4; n++) {
    int lg = q * 8192 + (wc * 64 + n * 16 + l16) * 32;
    brlo[n] = SWZB(lg);
    brhi[n] = SWZB(lg + 16);
  }

  // A fragment global pointers: lane-private row, q = k-quarter (32 B each)
  const unsigned char* ag[4];
#pragma unroll
  for (int m = 0; m < 4; m++)
    ag[m] = A + (size_t)(bm * 128 + wr * 64 + m * 16 + l16) * 4096 + q * 32;

  f32x4 acc[4][4] = {};
  i32x8 Xa0, Xa1, Xa2, Xa3, Ya0, Ya1, Ya2, Ya3;

  char* b0 = lds;
  char* b1 = lds + TILE_BYTES;
  char* b2 = lds + 2 * TILE_BYTES;

  // prologue: stage B(0)->b0, B(1)->b1; load A(0)->Xa; issue A(1)->Ya
#pragma unroll
  for (int i = 0; i < 4; i++) GLDS(bgp[i], b0 + boff[i]);
#pragma unroll
  for (int i = 0; i < 4; i++) GLDS(bgp[i] + 128, b1 + boff[i]);
  Xa0 = read_a(ag[0]); Xa1 = read_a(ag[1]); Xa2 = read_a(ag[2]); Xa3 = read_a(ag[3]);
  Ya0 = read_a(ag[0] + 128); Ya1 = read_a(ag[1] + 128);
  Ya2 = read_a(ag[2] + 128); Ya3 = read_a(ag[3] + 128);
  SB;
  asm volatile("s_waitcnt vmcnt(16)" ::: "memory");  // B(0),B(1) GLDS drained
  SB;
  __builtin_amdgcn_s_barrier();                      // publish B(0) (and B(1))

#pragma unroll 1
  for (int t = 0; t < 32; t += 2) {
    const int kb0 = ((t + 2) & 31) * 128;  // tail wraps -> dead stages/loads
    const int kb1 = ((t + 3) & 31) * 128;
    TBODY(b0, b2, Xa0, Xa1, Xa2, Xa3, kb0);  // body t   (A=Xa)
    TBODY(b1, b0, Ya0, Ya1, Ya2, Ya3, kb1);  // body t+1 (A=Ya)
    char* n0 = b2; char* n1 = b0; char* n2 = b1;
    b0 = n0; b1 = n1; b2 = n2;
  }

  asm volatile("s_waitcnt vmcnt(0) lgkmcnt(0)" ::: "memory");  // drain dead tail

  // epilogue: kv = bf16(exp(-gamma * max(f2 + p2 - 2*dot, 0)))
  // C/D layout (16x16): col = lane&15, row = (lane>>4)*4 + j
  float p2v[4];
#pragma unroll
  for (int n = 0; n < 4; n++) p2v[n] = p2[bn * 256 + wc * 64 + n * 16 + l16];
#pragma unroll
  for (int m = 0; m < 4; m++) {
#pragma unroll
    for (int j = 0; j < 4; j++) {
      int grow = bm * 128 + wr * 64 + m * 16 + q * 4 + j;
      float f2v = f2[grow];
      __hip_bfloat16* kvp = kv + (size_t)grow * 4096 + bn * 256 + wc * 64 + l16;
#pragma unroll
      for (int n = 0; n < 4; n++) {
        float d2 = fmaxf(f2v + p2v[n] - 2.0f * acc[m][n][j], 0.f);
        kvp[n * 16] = __float2bfloat16(__expf(-GAMMA * d2));
      }
    }
  }
}

// ---------------- Kernel 3: logits = kv @ head_w^T + b; log_softmax ----------------
// 4 rows/block, grid 512, low-VGPR (single w live; caps at 128 via launch_bounds).
__global__ __launch_bounds__(256, 4) void head_ls_k(
    const __hip_bfloat16* __restrict__ kv, const float* __restrict__ hw,
    const float* __restrict__ hb, float* __restrict__ out) {
  const int bb = blockIdx.x * 4;
  const int tid = threadIdx.x;
  float part[4][10];
#pragma unroll
  for (int r = 0; r < 4; r++)
#pragma unroll
    for (int c = 0; c < 10; c++) part[r][c] = 0.f;

#pragma unroll 1
  for (int k = 0; k < 4; k++) {
    const int idx = tid + k * 256;
    float a[4][4];
#pragma unroll
    for (int r = 0; r < 4; r++) {
      ushort4 v = ((const ushort4*)(kv + (size_t)(bb + r) * 4096))[idx];
      a[r][0] = bf2f(v.x); a[r][1] = bf2f(v.y); a[r][2] = bf2f(v.z); a[r][3] = bf2f(v.w);
    }
#pragma unroll
    for (int c = 0; c < 10; c++) {
      float4 w = *(const float4*)(hw + c * 4096 + idx * 4);
#pragma unroll
      for (int r = 0; r < 4; r++)
        part[r][c] += a[r][0] * w.x + a[r][1] * w.y + a[r][2] * w.z + a[r][3] * w.w;
    }
  }

#pragma unroll
  for (int r = 0; r < 4; r++)
#pragma unroll
    for (int c = 0; c < 10; c++)
      for (int off = 32; off > 0; off >>= 1) part[r][c] += __shfl_down(part[r][c], off);

  __shared__ float red[4][4][10];
  if ((tid & 63) == 0) {
#pragma unroll
    for (int r = 0; r < 4; r++)
#pragma unroll
      for (int c = 0; c < 10; c++) red[tid >> 6][r][c] = part[r][c];
  }
  __syncthreads();
  if (tid < 4) {
    const int r = tid;
    float l[10], m = -1e30f;
#pragma unroll
    for (int c = 0; c < 10; c++) {
      l[c] = red[0][r][c] + red[1][r][c] + red[2][r][c] + red[3][r][c] + hb[c];
      m = fmaxf(m, l[c]);
    }
    float s = 0.f;
#pragma unroll
    for (int c = 0; c < 10; c++) s += __expf(l[c] - m);
    float lse = logf(s);
#pragma unroll
    for (int c = 0; c < 10; c++) out[(size_t)(bb + r) * 10 + c] = l[c] - m - lse;
  }
}

extern "C" void kernel_launch(void* const* d_in, const int* in_sizes, int n_in,
                              void* d_out, int out_size, void* d_ws, size_t ws_size,
                              hipStream_t stream) {
  const float* x      = (const float*)d_in[0];
  const float* protos = (const float*)d_in[1];
  const float* conv_w = (const float*)d_in[2];
  const float* conv_b = (const float*)d_in[3];
  const float* head_w = (const float*)d_in[4];
  const float* head_b = (const float*)d_in[5];
  float* out = (float*)d_out;
  char* ws = (char*)d_ws;

  unsigned char* pB8  = (unsigned char*)ws;                      // 4096x4096 fp8 = 16 MB
  unsigned char* fA8  = (unsigned char*)(ws + (16u << 20));      // 2048x4096 fp8 =  8 MB
  __hip_bfloat16* kvb = (__hip_bfloat16*)(ws + (24u << 20));     // 2048x4096 bf16 = 16 MB
  float* f2 = (float*)(ws + (40u << 20));                        // 2048 f32
  float* p2 = (float*)(ws + (40u << 20) + 8192);                 // 4096 f32

  hipLaunchKernelGGL(prep_k, dim3(6144), dim3(256), 0, stream,
                     x, conv_w, conv_b, fA8, f2, protos, pB8, p2);
  hipLaunchKernelGGL(gemm_kv_k, dim3(256), dim3(512), 0, stream, fA8, pB8, f2, p2, kvb);
  hipLaunchKernelGGL(head_ls_k, dim3(512), dim3(256), 0, stream, kvb, head_w, head_b, out);
}

// Round 12
// 120.488 us; speedup vs baseline: 1.0502x; 1.0502x over previous
//
#include <hip/hip_runtime.h>
#include <hip/hip_bf16.h>
#include <stdint.h>

#define GAMMA 1e-4f

typedef int i32x4 __attribute__((ext_vector_type(4)));
typedef int i32x8 __attribute__((ext_vector_type(8)));
typedef float f32x4 __attribute__((ext_vector_type(4)));

__device__ __forceinline__ float bf2f(unsigned short u) {
  unsigned int x = ((unsigned int)u) << 16;
  float f; __builtin_memcpy(&f, &x, 4);
  return f;
}

// bit-exact float -> OCP e4m3fn (RNE, satfinite).
__device__ __forceinline__ unsigned char f2e4m3(float x) {
  float a = fabsf(x);
  unsigned char s = x < 0.f ? 0x80 : 0;
  a = fminf(a, 448.f);
  if (a < 0.015625f) {                    // subnormal region, ulp 2^-9
    int q = (int)rintf(a * 512.f);
    return s | (unsigned char)q;
  }
  unsigned int u; __builtin_memcpy(&u, &a, 4);
  u += 0x7FFFFu + ((u >> 20) & 1);        // RNE to 3 mantissa bits
  u &= 0xFFF00000u;
  int e2 = (int)(u >> 23) - 127;
  unsigned int mant = (u >> 20) & 7;
  return s | (unsigned char)(((e2 + 7) << 3) | mant);
}

__device__ __forceinline__ unsigned int pack4(float a, float b, float c, float d) {
  return (unsigned)f2e4m3(a) | ((unsigned)f2e4m3(b) << 8) |
         ((unsigned)f2e4m3(c) << 16) | ((unsigned)f2e4m3(d) << 24);
}

// ---------------- Kernel 1: merged prep (fp8 outputs, fp32 norms) ----------------
__global__ __launch_bounds__(256) void prep_k(
    const float* __restrict__ x, const float* __restrict__ cw,
    const float* __restrict__ cb, unsigned char* __restrict__ fA8,
    float* __restrict__ f2, const float* __restrict__ pr,
    unsigned char* __restrict__ pB8, float* __restrict__ p2) {
  const int tid = threadIdx.x;
  __shared__ float red[4];
  if (blockIdx.x < 4096) {
    const int j = blockIdx.x;
    const float4* src = (const float4*)(pr + (size_t)j * 4096);
    float ssq = 0.f;
    unsigned int w4[4];
#pragma unroll
    for (int k = 0; k < 4; k++) {
      float4 v = src[tid * 4 + k];
      ssq += v.x * v.x + v.y * v.y + v.z * v.z + v.w * v.w;
      w4[k] = pack4(v.x, v.y, v.z, v.w);
    }
    *(uint4*)(pB8 + (size_t)j * 4096 + tid * 16) = make_uint4(w4[0], w4[1], w4[2], w4[3]);
    for (int off = 32; off > 0; off >>= 1) ssq += __shfl_down(ssq, off);
    if ((tid & 63) == 0) red[tid >> 6] = ssq;
    __syncthreads();
    if (tid == 0) p2[j] = red[0] + red[1] + red[2] + red[3];
  } else {
    const int b = blockIdx.x - 4096;
    __shared__ float swb[20];
    if (tid < 16) swb[tid] = cw[tid];
    else if (tid < 20) swb[tid] = cb[tid - 16];
    __syncthreads();
    float w[16], bias[4];
#pragma unroll
    for (int i = 0; i < 16; i++) w[i] = swb[i];
#pragma unroll
    for (int c = 0; c < 4; c++) bias[c] = swb[16 + c];
    const float* xb = x + (size_t)b * 4096;
    unsigned char* fb8 = fA8 + (size_t)b * 4096;
    const int p0 = tid * 4;
    const int h = p0 >> 5, w0 = p0 & 31;
    const float* r0 = xb + (2 * h) * 64 + 2 * w0;
    const float* r1 = r0 + 64;
    float4 a0 = *(const float4*)r0, a1 = *(const float4*)(r0 + 4);
    float4 c0 = *(const float4*)r1, c1 = *(const float4*)(r1 + 4);
    float ssq = 0.f;
#pragma unroll
    for (int c = 0; c < 4; c++) {
      float w00 = w[c * 4], w01 = w[c * 4 + 1], w10 = w[c * 4 + 2], w11 = w[c * 4 + 3];
      float v0 = bias[c] + a0.x * w00 + a0.y * w01 + c0.x * w10 + c0.y * w11;
      float v1 = bias[c] + a0.z * w00 + a0.w * w01 + c0.z * w10 + c0.w * w11;
      float v2 = bias[c] + a1.x * w00 + a1.y * w01 + c1.x * w10 + c1.y * w11;
      float v3 = bias[c] + a1.z * w00 + a1.w * w01 + c1.z * w10 + c1.w * w11;
      ssq += v0 * v0 + v1 * v1 + v2 * v2 + v3 * v3;
      *(unsigned int*)(fb8 + c * 1024 + p0) = pack4(v0, v1, v2, v3);
    }
    for (int off = 32; off > 0; off >>= 1) ssq += __shfl_down(ssq, off);
    if ((tid & 63) == 0) red[tid >> 6] = ssq;
    __syncthreads();
    if (tid == 0) f2[b] = red[0] + red[1] + red[2] + red[3];
  }
}

// ---------------- Kernel 2: fp8 GEMM (16x16x128 mfma_scale) + RBF epilogue ------------
// m148-REPLICA: BM=BN=128, BK=128; 256 threads (4 waves, 2x2; wave tile 64x64);
// SINGLE 32 KiB LDS buffer -> 2 WGs co-resident per CU (decorrelated barriers =
// m114 cross-WG overlap); plain __syncthreads() x2 per K-tile; NO hand waits
// (m131-m141: explicit vmcnt/dbuf at source is neutral-to-harmful vs compiler).
// LDS: A [4 kq][128 rows][32B] @0 (16KB), B same @16384. Both-sides XOR swizzle
// phys = logical ^ (((logical>>12)&1)<<4) (R5/R8 geometry: measured 0 conflicts).
#define SWZ(o) ((o) ^ ((((o) >> 12) & 1) << 4))

#define GLDS(gsrc, ldst)                                                    \
  __builtin_amdgcn_global_load_lds(                                         \
      (__attribute__((address_space(1))) void*)(void*)(gsrc),               \
      (__attribute__((address_space(3))) void*)(ldst), 16, 0, 0)

#define MFMA8(a, b, c)                                                      \
  __builtin_amdgcn_mfma_scale_f32_16x16x128_f8f6f4(                         \
      (a), (b), (c), 0, 0, 0, 0x7f7f7f7fu, 0, 0x7f7f7f7fu)

__device__ __forceinline__ i32x8 read32(const char* p0, const char* p1) {
  i32x4 lo = *(const i32x4*)p0;
  i32x4 hi = *(const i32x4*)p1;
  return __builtin_shufflevector(lo, hi, 0, 1, 2, 3, 4, 5, 6, 7);
}

__global__ __launch_bounds__(256, 4) void gemm_kv_k(
    const unsigned char* __restrict__ A, const unsigned char* __restrict__ B,
    const float* __restrict__ f2, const float* __restrict__ p2,
    __hip_bfloat16* __restrict__ kv) {
  __shared__ __align__(16) char lds[32768];  // single buffer: A 16K + B 16K
  const int tid = threadIdx.x;
  const int wave = tid >> 6, lane = tid & 63;
  const int q = lane >> 4, l16 = lane & 15;
  const int wr = wave >> 1, wc = wave & 1;

  // XCD swizzle: 512 WGs = 8 XCDs x 64; each XCD owns a 4-wide bn strip (2MB of B).
  const int wg = blockIdx.x;
  const int xcd = wg & 7, loc = wg >> 3;
  const int bm = loc >> 2;             // 0..15
  const int bn = xcd * 4 + (loc & 3);  // 0..31

  // staging: linear LDS dest, inverse-swizzled global src (rule #21)
  const unsigned char* agp[4];
  const unsigned char* bgp[4];
  int aoff[4];
#pragma unroll
  for (int i = 0; i < 4; i++) {
    int phys = (tid + i * 256) * 16;   // [0,16384)
    aoff[i] = phys;
    int lg = SWZ(phys);
    int kq = lg >> 12, rw = (lg & 4095) >> 5, kl = lg & 31;
    agp[i] = A + (size_t)(bm * 128 + rw) * 4096 + kq * 32 + kl;
    bgp[i] = B + (size_t)(bn * 128 + rw) * 4096 + kq * 32 + kl;
  }

  // fragment read addresses (R5/R8-verified pattern, 0 conflicts)
  int arlo[4], arhi[4], brlo[4], brhi[4];
#pragma unroll
  for (int m = 0; m < 4; m++) {
    int lg = q * 4096 + (wr * 64 + m * 16 + l16) * 32;
    arlo[m] = SWZ(lg);
    arhi[m] = SWZ(lg + 16);
  }
#pragma unroll
  for (int n = 0; n < 4; n++) {
    int lg = q * 4096 + (wc * 64 + n * 16 + l16) * 32;
    brlo[n] = 16384 + SWZ(lg);
    brhi[n] = 16384 + SWZ(lg + 16);
  }

  f32x4 acc[4][4] = {};

#pragma unroll 1
  for (int t = 0; t < 32; ++t) {
    const int kb = t * 128;
    // stage tile t (single buffer; prev compute finished at loop-end barrier)
#pragma unroll
    for (int i = 0; i < 4; i++) GLDS(agp[i] + kb, lds + aoff[i]);
#pragma unroll
    for (int i = 0; i < 4; i++) GLDS(bgp[i] + kb, lds + 16384 + aoff[i]);
    __syncthreads();  // compiler drains vmcnt; publishes tile t

    i32x8 av0 = read32(lds + arlo[0], lds + arhi[0]);
    i32x8 av1 = read32(lds + arlo[1], lds + arhi[1]);
    i32x8 av2 = read32(lds + arlo[2], lds + arhi[2]);
    i32x8 av3 = read32(lds + arlo[3], lds + arhi[3]);
    i32x8 bv0 = read32(lds + brlo[0], lds + brhi[0]);
    i32x8 bv1 = read32(lds + brlo[1], lds + brhi[1]);
    i32x8 bv2 = read32(lds + brlo[2], lds + brhi[2]);
    i32x8 bv3 = read32(lds + brlo[3], lds + brhi[3]);

    acc[0][0] = MFMA8(av0, bv0, acc[0][0]);
    acc[0][1] = MFMA8(av0, bv1, acc[0][1]);
    acc[1][0] = MFMA8(av1, bv0, acc[1][0]);
    acc[1][1] = MFMA8(av1, bv1, acc[1][1]);
    acc[2][0] = MFMA8(av2, bv0, acc[2][0]);
    acc[2][1] = MFMA8(av2, bv1, acc[2][1]);
    acc[3][0] = MFMA8(av3, bv0, acc[3][0]);
    acc[3][1] = MFMA8(av3, bv1, acc[3][1]);
    acc[0][2] = MFMA8(av0, bv2, acc[0][2]);
    acc[0][3] = MFMA8(av0, bv3, acc[0][3]);
    acc[1][2] = MFMA8(av1, bv2, acc[1][2]);
    acc[1][3] = MFMA8(av1, bv3, acc[1][3]);
    acc[2][2] = MFMA8(av2, bv2, acc[2][2]);
    acc[2][3] = MFMA8(av2, bv3, acc[2][3]);
    acc[3][2] = MFMA8(av3, bv2, acc[3][2]);
    acc[3][3] = MFMA8(av3, bv3, acc[3][3]);

    __syncthreads();  // all waves done reading before next stage overwrites
  }

  // epilogue: kv = bf16(exp(-gamma * max(f2 + p2 - 2*dot, 0)))
  // C/D layout (16x16): col = lane&15, row = (lane>>4)*4 + j
  float p2v[4];
#pragma unroll
  for (int n = 0; n < 4; n++) p2v[n] = p2[bn * 128 + wc * 64 + n * 16 + l16];
#pragma unroll
  for (int m = 0; m < 4; m++) {
#pragma unroll
    for (int j = 0; j < 4; j++) {
      int grow = bm * 128 + wr * 64 + m * 16 + q * 4 + j;
      float f2v = f2[grow];
      __hip_bfloat16* kvp = kv + (size_t)grow * 4096 + bn * 128 + wc * 64 + l16;
#pragma unroll
      for (int n = 0; n < 4; n++) {
        float d2 = fmaxf(f2v + p2v[n] - 2.0f * acc[m][n][j], 0.f);
        kvp[n * 16] = __float2bfloat16(__expf(-GAMMA * d2));
      }
    }
  }
}

// ---------------- Kernel 3: logits = kv @ head_w^T + b; log_softmax ----------------
// 4 rows/block, grid 512, low-VGPR (single w live; caps at 128 via launch_bounds).
__global__ __launch_bounds__(256, 4) void head_ls_k(
    const __hip_bfloat16* __restrict__ kv, const float* __restrict__ hw,
    const float* __restrict__ hb, float* __restrict__ out) {
  const int bb = blockIdx.x * 4;
  const int tid = threadIdx.x;
  float part[4][10];
#pragma unroll
  for (int r = 0; r < 4; r++)
#pragma unroll
    for (int c = 0; c < 10; c++) part[r][c] = 0.f;

#pragma unroll 1
  for (int k = 0; k < 4; k++) {
    const int idx = tid + k * 256;
    float a[4][4];
#pragma unroll
    for (int r = 0; r < 4; r++) {
      ushort4 v = ((const ushort4*)(kv + (size_t)(bb + r) * 4096))[idx];
      a[r][0] = bf2f(v.x); a[r][1] = bf2f(v.y); a[r][2] = bf2f(v.z); a[r][3] = bf2f(v.w);
    }
#pragma unroll
    for (int c = 0; c < 10; c++) {
      float4 w = *(const float4*)(hw + c * 4096 + idx * 4);
#pragma unroll
      for (int r = 0; r < 4; r++)
        part[r][c] += a[r][0] * w.x + a[r][1] * w.y + a[r][2] * w.z + a[r][3] * w.w;
    }
  }

#pragma unroll
  for (int r = 0; r < 4; r++)
#pragma unroll
    for (int c = 0; c < 10; c++)
      for (int off = 32; off > 0; off >>= 1) part[r][c] += __shfl_down(part[r][c], off);

  __shared__ float red[4][4][10];
  if ((tid & 63) == 0) {
#pragma unroll
    for (int r = 0; r < 4; r++)
#pragma unroll
      for (int c = 0; c < 10; c++) red[tid >> 6][r][c] = part[r][c];
  }
  __syncthreads();
  if (tid < 4) {
    const int r = tid;
    float l[10], m = -1e30f;
#pragma unroll
    for (int c = 0; c < 10; c++) {
      l[c] = red[0][r][c] + red[1][r][c] + red[2][r][c] + red[3][r][c] + hb[c];
      m = fmaxf(m, l[c]);
    }
    float s = 0.f;
#pragma unroll
    for (int c = 0; c < 10; c++) s += __expf(l[c] - m);
    float lse = logf(s);
#pragma unroll
    for (int c = 0; c < 10; c++) out[(size_t)(bb + r) * 10 + c] = l[c] - m - lse;
  }
}

extern "C" void kernel_launch(void* const* d_in, const int* in_sizes, int n_in,
                              void* d_out, int out_size, void* d_ws, size_t ws_size,
                              hipStream_t stream) {
  const float* x      = (const float*)d_in[0];
  const float* protos = (const float*)d_in[1];
  const float* conv_w = (const float*)d_in[2];
  const float* conv_b = (const float*)d_in[3];
  const float* head_w = (const float*)d_in[4];
  const float* head_b = (const float*)d_in[5];
  float* out = (float*)d_out;
  char* ws = (char*)d_ws;

  unsigned char* pB8  = (unsigned char*)ws;                      // 4096x4096 fp8 = 16 MB
  unsigned char* fA8  = (unsigned char*)(ws + (16u << 20));      // 2048x4096 fp8 =  8 MB
  __hip_bfloat16* kvb = (__hip_bfloat16*)(ws + (24u << 20));     // 2048x4096 bf16 = 16 MB
  float* f2 = (float*)(ws + (40u << 20));                        // 2048 f32
  float* p2 = (float*)(ws + (40u << 20) + 8192);                 // 4096 f32

  hipLaunchKernelGGL(prep_k, dim3(6144), dim3(256), 0, stream,
                     x, conv_w, conv_b, fA8, f2, protos, pB8, p2);
  hipLaunchKernelGGL(gemm_kv_k, dim3(512), dim3(256), 0, stream, fA8, pB8, f2, p2, kvb);
  hipLaunchKernelGGL(head_ls_k, dim3(512), dim3(256), 0, stream, kvb, head_w, head_b, out);
}

// Round 13
// 90.355 us; speedup vs baseline: 1.4004x; 1.3335x over previous
//
#include <hip/hip_runtime.h>
#include <hip/hip_bf16.h>
#include <stdint.h>

#define GAMMA 1e-4f

typedef int i32x4 __attribute__((ext_vector_type(4)));
typedef int i32x8 __attribute__((ext_vector_type(8)));
typedef float f32x4 __attribute__((ext_vector_type(4)));

__device__ __forceinline__ float bf2f(unsigned short u) {
  unsigned int x = ((unsigned int)u) << 16;
  float f; __builtin_memcpy(&f, &x, 4);
  return f;
}

// bit-exact float -> OCP e4m3fn (RNE, satfinite).
__device__ __forceinline__ unsigned char f2e4m3(float x) {
  float a = fabsf(x);
  unsigned char s = x < 0.f ? 0x80 : 0;
  a = fminf(a, 448.f);
  if (a < 0.015625f) {                    // subnormal region, ulp 2^-9
    int q = (int)rintf(a * 512.f);
    return s | (unsigned char)q;
  }
  unsigned int u; __builtin_memcpy(&u, &a, 4);
  u += 0x7FFFFu + ((u >> 20) & 1);        // RNE to 3 mantissa bits
  u &= 0xFFF00000u;
  int e2 = (int)(u >> 23) - 127;
  unsigned int mant = (u >> 20) & 7;
  return s | (unsigned char)(((e2 + 7) << 3) | mant);
}

__device__ __forceinline__ unsigned int pack4(float a, float b, float c, float d) {
  return (unsigned)f2e4m3(a) | ((unsigned)f2e4m3(b) << 8) |
         ((unsigned)f2e4m3(c) << 16) | ((unsigned)f2e4m3(d) << 24);
}

// ---------------- Kernel 1: merged prep ----------------
// protos -> linear fp8 pB8 + p2 (unchanged).
// conv feats -> fp8 in MFMA-FRAGMENT-ORDER A'' layout + f2:
//   A''[g=row>>4][kt=k>>7][half=(k>>4)&1][lane=(row&15)+16*((k>>5)&3)][k&15]
//   flat off = g*65536 + kt*2048 + half*1024 + lane*16 + (k&15)
__global__ __launch_bounds__(256) void prep_k(
    const float* __restrict__ x, const float* __restrict__ cw,
    const float* __restrict__ cb, unsigned char* __restrict__ fA8,
    float* __restrict__ f2, const float* __restrict__ pr,
    unsigned char* __restrict__ pB8, float* __restrict__ p2) {
  const int tid = threadIdx.x;
  __shared__ float red[4];
  if (blockIdx.x < 4096) {
    const int j = blockIdx.x;
    const float4* src = (const float4*)(pr + (size_t)j * 4096);
    float ssq = 0.f;
    unsigned int w4[4];
#pragma unroll
    for (int k = 0; k < 4; k++) {
      float4 v = src[tid * 4 + k];
      ssq += v.x * v.x + v.y * v.y + v.z * v.z + v.w * v.w;
      w4[k] = pack4(v.x, v.y, v.z, v.w);
    }
    *(uint4*)(pB8 + (size_t)j * 4096 + tid * 16) = make_uint4(w4[0], w4[1], w4[2], w4[3]);
    for (int off = 32; off > 0; off >>= 1) ssq += __shfl_down(ssq, off);
    if ((tid & 63) == 0) red[tid >> 6] = ssq;
    __syncthreads();
    if (tid == 0) p2[j] = red[0] + red[1] + red[2] + red[3];
  } else {
    const int b = blockIdx.x - 4096;
    __shared__ float swb[20];
    if (tid < 16) swb[tid] = cw[tid];
    else if (tid < 20) swb[tid] = cb[tid - 16];
    __syncthreads();
    float w[16], bias[4];
#pragma unroll
    for (int i = 0; i < 16; i++) w[i] = swb[i];
#pragma unroll
    for (int c = 0; c < 4; c++) bias[c] = swb[16 + c];
    const float* xb = x + (size_t)b * 4096;
    const int p0 = tid * 4;
    const int h = p0 >> 5, w0 = p0 & 31;
    const float* r0 = xb + (2 * h) * 64 + 2 * w0;
    const float* r1 = r0 + 64;
    float4 a0 = *(const float4*)r0, a1 = *(const float4*)(r0 + 4);
    float4 c0 = *(const float4*)r1, c1 = *(const float4*)(r1 + 4);
    // A'' destination pieces independent of c:
    const size_t gbase = (size_t)(b >> 4) * 65536;
    const int half = (tid >> 2) & 1;
    const int lane = (b & 15) + 16 * ((tid >> 3) & 3);
    const int bofs = 4 * (tid & 3);
    const int ktsub = tid >> 5;            // kt = c*8 + ktsub
    float ssq = 0.f;
#pragma unroll
    for (int c = 0; c < 4; c++) {
      float w00 = w[c * 4], w01 = w[c * 4 + 1], w10 = w[c * 4 + 2], w11 = w[c * 4 + 3];
      float v0 = bias[c] + a0.x * w00 + a0.y * w01 + c0.x * w10 + c0.y * w11;
      float v1 = bias[c] + a0.z * w00 + a0.w * w01 + c0.z * w10 + c0.w * w11;
      float v2 = bias[c] + a1.x * w00 + a1.y * w01 + c1.x * w10 + c1.y * w11;
      float v3 = bias[c] + a1.z * w00 + a1.w * w01 + c1.z * w10 + c1.w * w11;
      ssq += v0 * v0 + v1 * v1 + v2 * v2 + v3 * v3;
      size_t off = gbase + (size_t)(c * 8 + ktsub) * 2048 + half * 1024 + lane * 16 + bofs;
      *(unsigned int*)(fA8 + off) = pack4(v0, v1, v2, v3);
    }
    for (int off = 32; off > 0; off >>= 1) ssq += __shfl_down(ssq, off);
    if ((tid & 63) == 0) red[tid >> 6] = ssq;
    __syncthreads();
    if (tid == 0) f2[b] = red[0] + red[1] + red[2] + red[3];
  }
}

// ---------------- Kernel 2: fp8 GEMM (16x16x128 mfma_scale) + RBF epilogue ------------
// BM=BN=128, BK=128; 256 threads (4 waves, 2x2; wave tile 64x64).
// A: DIRECT GLOBAL->REG from fragment-ordered A'' (1KB-contiguous per load, L1/L2-hot),
//    register double-buffered (X/Y sets).
// B: LDS ring-2 x 16 KiB = 32 KiB total -> 2-3 WGs/CU co-resident (m114 overlap).
// Per body: {8 B ds_reads | 4 B-GLDS(t+1) | 8 A-loads(t+1) -> vmcnt(12)+lgkm(0) ->
//            16 MFMA -> vmcnt(8) -> s_barrier}.  In-order VMEM: 12 issued/body.
#define SWZ(o) ((o) ^ ((((o) >> 12) & 1) << 4))

#define GLDS(gsrc, ldst)                                                    \
  __builtin_amdgcn_global_load_lds(                                         \
      (__attribute__((address_space(1))) void*)(void*)(gsrc),               \
      (__attribute__((address_space(3))) void*)(ldst), 16, 0, 0)

#define MFMA8(a, b, c)                                                      \
  __builtin_amdgcn_mfma_scale_f32_16x16x128_f8f6f4(                         \
      (a), (b), (c), 0, 0, 0, 0x7f7f7f7fu, 0, 0x7f7f7f7fu)

__device__ __forceinline__ i32x8 read32(const char* p0, const char* p1) {
  i32x4 lo = *(const i32x4*)p0;
  i32x4 hi = *(const i32x4*)p1;
  return __builtin_shufflevector(lo, hi, 0, 1, 2, 3, 4, 5, 6, 7);
}
__device__ __forceinline__ i32x8 read_a(const unsigned char* p) {
  i32x4 lo = *(const i32x4*)p;            // lane-contiguous 1KB across the wave
  i32x4 hi = *(const i32x4*)(p + 1024);   // second half-plane, also contiguous
  return __builtin_shufflevector(lo, hi, 0, 1, 2, 3, 4, 5, 6, 7);
}

#define SB __builtin_amdgcn_sched_barrier(0)

// body: B frags(t) from CUR; stage B(KTN)->NXT; load A(KTN)->AY; MFMA on AX.
#define TBODY(CUR, NXT, KTN, AX0, AX1, AX2, AX3, AY0, AY1, AY2, AY3)        \
  {                                                                         \
    i32x8 bv0, bv1, bv2, bv3;                                               \
    SB;                                                                     \
    bv0 = read32((CUR) + brlo[0], (CUR) + brhi[0]);                         \
    bv1 = read32((CUR) + brlo[1], (CUR) + brhi[1]);                         \
    bv2 = read32((CUR) + brlo[2], (CUR) + brhi[2]);                         \
    bv3 = read32((CUR) + brlo[3], (CUR) + brhi[3]);                         \
    SB;                                                                     \
    GLDS(bgp[0] + (size_t)(KTN) * 128, (NXT) + boff[0]);                    \
    GLDS(bgp[1] + (size_t)(KTN) * 128, (NXT) + boff[1]);                    \
    GLDS(bgp[2] + (size_t)(KTN) * 128, (NXT) + boff[2]);                    \
    GLDS(bgp[3] + (size_t)(KTN) * 128, (NXT) + boff[3]);                    \
    SB;                                                                     \
    AY0 = read_a(agb[0] + (size_t)(KTN) * 2048);                            \
    AY1 = read_a(agb[1] + (size_t)(KTN) * 2048);                            \
    AY2 = read_a(agb[2] + (size_t)(KTN) * 2048);                            \
    AY3 = read_a(agb[3] + (size_t)(KTN) * 2048);                            \
    SB;                                                                     \
    asm volatile("s_waitcnt vmcnt(12) lgkmcnt(0)" ::: "memory");            \
    SB;                                                                     \
    __builtin_amdgcn_s_setprio(1);                                          \
    acc[0][0] = MFMA8(AX0, bv0, acc[0][0]);                                 \
    acc[0][1] = MFMA8(AX0, bv1, acc[0][1]);                                 \
    acc[1][0] = MFMA8(AX1, bv0, acc[1][0]);                                 \
    acc[1][1] = MFMA8(AX1, bv1, acc[1][1]);                                 \
    acc[2][0] = MFMA8(AX2, bv0, acc[2][0]);                                 \
    acc[2][1] = MFMA8(AX2, bv1, acc[2][1]);                                 \
    acc[3][0] = MFMA8(AX3, bv0, acc[3][0]);                                 \
    acc[3][1] = MFMA8(AX3, bv1, acc[3][1]);                                 \
    acc[0][2] = MFMA8(AX0, bv2, acc[0][2]);                                 \
    acc[0][3] = MFMA8(AX0, bv3, acc[0][3]);                                 \
    acc[1][2] = MFMA8(AX1, bv2, acc[1][2]);                                 \
    acc[1][3] = MFMA8(AX1, bv3, acc[1][3]);                                 \
    acc[2][2] = MFMA8(AX2, bv2, acc[2][2]);                                 \
    acc[2][3] = MFMA8(AX2, bv3, acc[2][3]);                                 \
    acc[3][2] = MFMA8(AX3, bv2, acc[3][2]);                                 \
    acc[3][3] = MFMA8(AX3, bv3, acc[3][3]);                                 \
    __builtin_amdgcn_s_setprio(0);                                          \
    SB;                                                                     \
    asm volatile("s_waitcnt vmcnt(8)" ::: "memory");                        \
    SB;                                                                     \
    __builtin_amdgcn_s_barrier();                                           \
  }

__global__ __launch_bounds__(256, 2) void gemm_kv_k(
    const unsigned char* __restrict__ A, const unsigned char* __restrict__ B,
    const float* __restrict__ f2, const float* __restrict__ p2,
    __hip_bfloat16* __restrict__ kv) {
  __shared__ __align__(16) char lds[32768];  // B only: 2 x 16 KiB ring
  const int tid = threadIdx.x;
  const int wave = tid >> 6, lane = tid & 63;
  const int q = lane >> 4, l16 = lane & 15;
  const int wr = wave >> 1, wc = wave & 1;

  // XCD swizzle: 512 WGs = 8 XCDs x 64; each XCD owns a 4-wide bn strip.
  const int wg = blockIdx.x;
  const int xcd = wg & 7, loc = wg >> 3;
  const int bm = loc >> 2;             // 0..15
  const int bn = xcd * 4 + (loc & 3);  // 0..31

  // B staging: linear LDS dest, inverse-swizzled global src (rule #21)
  const unsigned char* bgp[4];
  int boff[4];
#pragma unroll
  for (int i = 0; i < 4; i++) {
    int phys = (tid + i * 256) * 16;   // [0,16384)
    boff[i] = phys;
    int lg = SWZ(phys);
    int kq = lg >> 12, rw = (lg & 4095) >> 5, kl = lg & 31;
    bgp[i] = B + (size_t)(bn * 128 + rw) * 4096 + kq * 32 + kl;
  }

  // B fragment LDS offsets (R8-verified, 0 conflicts)
  int brlo[4], brhi[4];
#pragma unroll
  for (int n = 0; n < 4; n++) {
    int lg = q * 4096 + (wc * 64 + n * 16 + l16) * 32;
    brlo[n] = SWZ(lg);
    brhi[n] = SWZ(lg + 16);
  }

  // A fragment global base (fragment-ordered A''): contiguous 1KB per wave-load
  const unsigned char* agb[4];
#pragma unroll
  for (int m = 0; m < 4; m++)
    agb[m] = A + (size_t)(bm * 8 + wr * 4 + m) * 65536 + (l16 + 16 * q) * 16;

  f32x4 acc[4][4] = {};
  i32x8 Xa0, Xa1, Xa2, Xa3, Ya0, Ya1, Ya2, Ya3;

  char* buf0 = lds;
  char* buf1 = lds + 16384;

  // prologue: stage B(0); load A(0)->X
#pragma unroll
  for (int i = 0; i < 4; i++) GLDS(bgp[i], buf0 + boff[i]);
  Xa0 = read_a(agb[0]); Xa1 = read_a(agb[1]);
  Xa2 = read_a(agb[2]); Xa3 = read_a(agb[3]);
  SB;
  asm volatile("s_waitcnt vmcnt(8)" ::: "memory");  // B(0) GLDS drained; A(0) may fly
  SB;
  __builtin_amdgcn_s_barrier();

#pragma unroll 1
  for (int t = 0; t < 32; t += 2) {
    const int k1 = (t + 1) & 31;  // t=31 path wraps -> dead loads, drained after loop
    const int k2 = (t + 2) & 31;
    TBODY(buf0, buf1, k1, Xa0, Xa1, Xa2, Xa3, Ya0, Ya1, Ya2, Ya3);
    TBODY(buf1, buf0, k2, Ya0, Ya1, Ya2, Ya3, Xa0, Xa1, Xa2, Xa3);
  }

  asm volatile("s_waitcnt vmcnt(0) lgkmcnt(0)" ::: "memory");  // drain dead tail

  // epilogue: kv = bf16(exp(-gamma * max(f2 + p2 - 2*dot, 0)))
  // C/D layout (16x16): col = lane&15, row = (lane>>4)*4 + j
  float p2v[4];
#pragma unroll
  for (int n = 0; n < 4; n++) p2v[n] = p2[bn * 128 + wc * 64 + n * 16 + l16];
#pragma unroll
  for (int m = 0; m < 4; m++) {
#pragma unroll
    for (int j = 0; j < 4; j++) {
      int grow = bm * 128 + wr * 64 + m * 16 + q * 4 + j;
      float f2v = f2[grow];
      __hip_bfloat16* kvp = kv + (size_t)grow * 4096 + bn * 128 + wc * 64 + l16;
#pragma unroll
      for (int n = 0; n < 4; n++) {
        float d2 = fmaxf(f2v + p2v[n] - 2.0f * acc[m][n][j], 0.f);
        kvp[n * 16] = __float2bfloat16(__expf(-GAMMA * d2));
      }
    }
  }
}

// ---------------- Kernel 3: logits = kv @ head_w^T + b; log_softmax ----------------
// 4 rows/block, grid 512, low-VGPR (single w live; caps at 128 via launch_bounds).
__global__ __launch_bounds__(256, 4) void head_ls_k(
    const __hip_bfloat16* __restrict__ kv, const float* __restrict__ hw,
    const float* __restrict__ hb, float* __restrict__ out) {
  const int bb = blockIdx.x * 4;
  const int tid = threadIdx.x;
  float part[4][10];
#pragma unroll
  for (int r = 0; r < 4; r++)
#pragma unroll
    for (int c = 0; c < 10; c++) part[r][c] = 0.f;

#pragma unroll 1
  for (int k = 0; k < 4; k++) {
    const int idx = tid + k * 256;
    float a[4][4];
#pragma unroll
    for (int r = 0; r < 4; r++) {
      ushort4 v = ((const ushort4*)(kv + (size_t)(bb + r) * 4096))[idx];
      a[r][0] = bf2f(v.x); a[r][1] = bf2f(v.y); a[r][2] = bf2f(v.z); a[r][3] = bf2f(v.w);
    }
#pragma unroll
    for (int c = 0; c < 10; c++) {
      float4 w = *(const float4*)(hw + c * 4096 + idx * 4);
#pragma unroll
      for (int r = 0; r < 4; r++)
        part[r][c] += a[r][0] * w.x + a[r][1] * w.y + a[r][2] * w.z + a[r][3] * w.w;
    }
  }

#pragma unroll
  for (int r = 0; r < 4; r++)
#pragma unroll
    for (int c = 0; c < 10; c++)
      for (int off = 32; off > 0; off >>= 1) part[r][c] += __shfl_down(part[r][c], off);

  __shared__ float red[4][4][10];
  if ((tid & 63) == 0) {
#pragma unroll
    for (int r = 0; r < 4; r++)
#pragma unroll
      for (int c = 0; c < 10; c++) red[tid >> 6][r][c] = part[r][c];
  }
  __syncthreads();
  if (tid < 4) {
    const int r = tid;
    float l[10], m = -1e30f;
#pragma unroll
    for (int c = 0; c < 10; c++) {
      l[c] = red[0][r][c] + red[1][r][c] + red[2][r][c] + red[3][r][c] + hb[c];
      m = fmaxf(m, l[c]);
    }
    float s = 0.f;
#pragma unroll
    for (int c = 0; c < 10; c++) s += __expf(l[c] - m);
    float lse = logf(s);
#pragma unroll
    for (int c = 0; c < 10; c++) out[(size_t)(bb + r) * 10 + c] = l[c] - m - lse;
  }
}

extern "C" void kernel_launch(void* const* d_in, const int* in_sizes, int n_in,
                              void* d_out, int out_size, void* d_ws, size_t ws_size,
                              hipStream_t stream) {
  const float* x      = (const float*)d_in[0];
  const float* protos = (const float*)d_in[1];
  const float* conv_w = (const float*)d_in[2];
  const float* conv_b = (const float*)d_in[3];
  const float* head_w = (const float*)d_in[4];
  const float* head_b = (const float*)d_in[5];
  float* out = (float*)d_out;
  char* ws = (char*)d_ws;

  unsigned char* pB8  = (unsigned char*)ws;                      // 4096x4096 fp8 = 16 MB
  unsigned char* fA8  = (unsigned char*)(ws + (16u << 20));      // 2048x4096 fp8 (A'' layout) = 8 MB
  __hip_bfloat16* kvb = (__hip_bfloat16*)(ws + (24u << 20));     // 2048x4096 bf16 = 16 MB
  float* f2 = (float*)(ws + (40u << 20));                        // 2048 f32
  float* p2 = (float*)(ws + (40u << 20) + 8192);                 // 4096 f32

  hipLaunchKernelGGL(prep_k, dim3(6144), dim3(256), 0, stream,
                     x, conv_w, conv_b, fA8, f2, protos, pB8, p2);
  hipLaunchKernelGGL(gemm_kv_k, dim3(512), dim3(256), 0, stream, fA8, pB8, f2, p2, kvb);
  hipLaunchKernelGGL(head_ls_k, dim3(512), dim3(256), 0, stream, kvb, head_w, head_b, out);
}